// Round 3
// baseline (422.415 us; speedup 1.0000x reference)
//
#include <hip/hip_runtime.h>
#include <hip/hip_bf16.h>
#include <math.h>

#define T_TOK 8192
#define DM 1024
#define DE 512
#define NE 8
#define DFF 4096

// converted-bf16 workspace layout (element offsets)
#define CO_X   0
#define CO_W1  8388608
#define CO_W2  12582912
#define CO_B1  16777216
#define CO_B2  16781312
#define CO_CE  16789504
#define CO_WR  16797696
#define CO_TOT 16805888

typedef __attribute__((ext_vector_type(8))) __bf16 bf16x8;
typedef __attribute__((ext_vector_type(4))) __bf16 bf16x4;
typedef __attribute__((ext_vector_type(8))) unsigned short u16x8;
typedef __attribute__((ext_vector_type(4))) float f32x4;
typedef __attribute__((ext_vector_type(4))) unsigned int u32x4;

// ---------------- dtype detection: 0 = fp32 inputs, 1 = bf16 inputs --------
__global__ __launch_bounds__(256) void detect_k(const void* xp, int* flag)
{
  const float* xf = (const float*)xp;
  int ok = 0;
  for (int i = threadIdx.x; i < 1024; i += 256){
    float a = fabsf(xf[i]);
    if (a > 1e-8f && a < 100.f) ok++;  // NaN compares false
  }
  __shared__ int cnt;
  if (threadIdx.x == 0) cnt = 0;
  __syncthreads();
  atomicAdd(&cnt, ok);
  __syncthreads();
  if (threadIdx.x == 0) *flag = (cnt > 512) ? 0 : 1;
}

// ---------------- fp32 -> bf16 conversion of all params (fp32 mode only) ---
__global__ __launch_bounds__(256) void convert_k(
    const float* __restrict__ x, const float* __restrict__ w1,
    const float* __restrict__ b1, const float* __restrict__ w2,
    const float* __restrict__ b2, const float* __restrict__ ce,
    const float* __restrict__ wr, __bf16* __restrict__ dst,
    const int* __restrict__ flag)
{
  if (*flag) return;  // bf16 mode: nothing to do
  const size_t i = ((size_t)blockIdx.x * 256 + threadIdx.x) * 4;
  const float* src; size_t off;
  if      (i < CO_W1){ src = x;  off = i - CO_X;  }
  else if (i < CO_W2){ src = w1; off = i - CO_W1; }
  else if (i < CO_B1){ src = w2; off = i - CO_W2; }
  else if (i < CO_B2){ src = b1; off = i - CO_B1; }
  else if (i < CO_CE){ src = b2; off = i - CO_B2; }
  else if (i < CO_WR){ src = ce; off = i - CO_CE; }
  else               { src = wr; off = i - CO_WR; }
  f32x4 v = *(const f32x4*)(src + off);
  bf16x4 o;
  #pragma unroll
  for (int j = 0; j < 4; j++) o[j] = (__bf16)v[j];
  *(bf16x4*)(dst + i) = o;
}

// load 16 consecutive floats at element offset `off`, either dtype
__device__ __forceinline__ void ld16(const void* p, size_t off, int md, float* o)
{
  if (md){
    const __bf16* b = (const __bf16*)p + off;
    bf16x8 v0 = *(const bf16x8*)b, v1 = *(const bf16x8*)(b + 8);
    #pragma unroll
    for (int i = 0; i < 8; i++){ o[i] = (float)v0[i]; o[i + 8] = (float)v1[i]; }
  } else {
    const float* f = (const float*)p + off;
    f32x4 a = *(const f32x4*)f, b = *(const f32x4*)(f + 4),
          c = *(const f32x4*)(f + 8), d = *(const f32x4*)(f + 12);
    #pragma unroll
    for (int i = 0; i < 4; i++){
      o[i] = a[i]; o[4 + i] = b[i]; o[8 + i] = c[i]; o[12 + i] = d[i];
    }
  }
}

// ---------------- routing: one wave per token, full input precision --------
__global__ __launch_bounds__(256) void route_k(
    const void* __restrict__ xp, const void* __restrict__ cp,
    const void* __restrict__ wp, const int* __restrict__ flag,
    float* __restrict__ gates)  // [T][NE]
{
  const int md = *flag;
  const int wv = threadIdx.x >> 6, ln = threadIdx.x & 63;
  const int t = (blockIdx.x << 2) + wv;

  float xv[16];
  ld16(xp, (size_t)t * DM + ln * 16, md, xv);

  float ss = 0.f;
  #pragma unroll
  for (int i = 0; i < 16; i++) ss += xv[i] * xv[i];
  #pragma unroll
  for (int m = 1; m < 64; m <<= 1) ss += __shfl_xor(ss, m, 64);
  const float xn = fmaxf(sqrtf(ss), 1e-12f);

  float logits[NE];
  for (int e = 0; e < NE; e++){
    float cv[16], wvv[16];
    ld16(cp, (size_t)e * DM + ln * 16, md, cv);
    ld16(wp, (size_t)e * DM + ln * 16, md, wvv);
    float cd = 0.f, cs = 0.f, wd = 0.f;
    #pragma unroll
    for (int i = 0; i < 16; i++){
      cd += xv[i] * cv[i]; cs += cv[i] * cv[i]; wd += xv[i] * wvv[i];
    }
    #pragma unroll
    for (int m = 1; m < 64; m <<= 1){
      cd += __shfl_xor(cd, m, 64);
      cs += __shfl_xor(cs, m, 64);
      wd += __shfl_xor(wd, m, 64);
    }
    logits[e] = cd / (xn * fmaxf(sqrtf(cs), 1e-12f)) + wd;
  }

  if (ln == 0){
    // top-2, reference tie semantics: thresh = 2nd-largest value, mask >= thresh
    float m1 = -1e30f; int i1 = 0;
    for (int e = 0; e < NE; e++) if (logits[e] > m1){ m1 = logits[e]; i1 = e; }
    float m2 = -1e30f;
    for (int e = 0; e < NE; e++) if (e != i1 && logits[e] > m2) m2 = logits[e];
    float ex[NE]; float denom = 0.f;
    for (int e = 0; e < NE; e++){
      if (logits[e] >= m2){ ex[e] = expf(logits[e] - m1); denom += ex[e]; }
      else ex[e] = 0.f;
    }
    const float inv = 1.f / denom;
    for (int e = 0; e < NE; e++) gates[t * NE + e] = ex[e] * inv;
  }
}

// ---------------- GEMM: 128x128 tile, BK=32, 4 waves of 64x64 ----------------
// MODE 0: Hp[t][e*512+j] = gate[t][e] * gelu( (x @ w1_e)[t][j] + b1[e][j] )
// MODE 1: out[t][d] = (Hp @ W2)[t][d] + sum_e gate[t][e]*b2[e][d]
template<int MODE>
__global__ __launch_bounds__(256) void gemm_k(
    const void* __restrict__ Ap, const void* __restrict__ Bpv,
    const void* __restrict__ biasv, const __bf16* __restrict__ conv,
    const int* __restrict__ flag, const float* __restrict__ gates,
    void* __restrict__ Cp)
{
  constexpr int K   = (MODE == 0) ? DM : DFF;
  constexpr int ldb = (MODE == 0) ? DE : DM;
  constexpr int ldc = (MODE == 0) ? DFF : DM;

  const int md = *flag;
  const __bf16* A = (MODE == 1) ? (const __bf16*)Ap
                                : (md ? (const __bf16*)Ap : conv + CO_X);
  const __bf16* B = md ? (const __bf16*)Bpv
                       : conv + (MODE == 0 ? CO_W1 : CO_W2);
  const __bf16* bias = md ? (const __bf16*)biasv
                          : conv + (MODE == 0 ? CO_B1 : CO_B2);

  // A tile: [128 rows][32 k], stride 40 (16B-aligned rows, <=2-way banks)
  __shared__ __attribute__((aligned(16))) __bf16 As[128 * 40];
  // B tile transposed+packed: [128 n][16 u32], u32 kp = {k=2kp, k=2kp+1}; stride 20
  __shared__ __attribute__((aligned(16))) unsigned int Bs[128 * 20];

  const int tid = threadIdx.x;
  const int m0 = blockIdx.x * 128;
  const int n0 = blockIdx.y * 128;
  const __bf16* Bp = (MODE == 0)
      ? (B + (size_t)(n0 >> 9) * ((size_t)K * DE) + (n0 & 511))
      : (B + n0);

  const int wv = tid >> 6, lane = tid & 63;
  const int q = lane >> 4, ln = lane & 15;
  const int wm = (wv >> 1) * 64, wn = (wv & 1) * 64;

  f32x4 acc[4][4] = {};

  // A staging: 128 rows x 32 k; 256 thr x 16 elems (two bf16x8)
  const int arow = tid >> 1, aseg = (tid & 1) * 16;
  const int bkp = tid & 15, bnc = (tid >> 4) * 8;

  const __bf16* Ag = A + (size_t)(m0 + arow) * K + aseg;
  const __bf16* Bg = Bp + (size_t)(2 * bkp) * ldb + bnc;

  for (int k0 = 0; k0 < K; k0 += 32){
    *(bf16x8*)&As[arow * 40 + aseg]     = *(const bf16x8*)(Ag + k0);
    *(bf16x8*)&As[arow * 40 + aseg + 8] = *(const bf16x8*)(Ag + k0 + 8);
    bf16x8 r0 = *(const bf16x8*)(Bg + (size_t)k0 * ldb);
    bf16x8 r1 = *(const bf16x8*)(Bg + (size_t)k0 * ldb + ldb);
    u16x8 s0 = __builtin_bit_cast(u16x8, r0);
    u16x8 s1 = __builtin_bit_cast(u16x8, r1);
    #pragma unroll
    for (int j = 0; j < 8; j++){
      Bs[(bnc + j) * 20 + bkp] = (unsigned)s0[j] | ((unsigned)s1[j] << 16);
    }
    __syncthreads();

    bf16x8 af[4], bfv[4];
    #pragma unroll
    for (int mi = 0; mi < 4; mi++)
      af[mi] = *(const bf16x8*)&As[(wm + mi * 16 + ln) * 40 + q * 8];
    #pragma unroll
    for (int ni = 0; ni < 4; ni++){
      u32x4 bw = *(const u32x4*)&Bs[(wn + ni * 16 + ln) * 20 + q * 4];
      bfv[ni] = __builtin_bit_cast(bf16x8, bw);
    }
    #pragma unroll
    for (int mi = 0; mi < 4; mi++)
      #pragma unroll
      for (int ni = 0; ni < 4; ni++)
        acc[mi][ni] = __builtin_amdgcn_mfma_f32_16x16x32_bf16(
            af[mi], bfv[ni], acc[mi][ni], 0, 0, 0);
    __syncthreads();
  }

  // epilogue: C/D layout col = lane&15, row = (lane>>4)*4 + reg  [m89-verified]
  if (MODE == 0){
    __bf16* C = (__bf16*)Cp;
    const int e = n0 >> 9;  // 128-col tile lies in one expert (128 | 512)
    float bset[4];
    #pragma unroll
    for (int ni = 0; ni < 4; ni++) bset[ni] = (float)bias[n0 + wn + ni * 16 + ln];
    #pragma unroll
    for (int mi = 0; mi < 4; mi++){
      #pragma unroll
      for (int r = 0; r < 4; r++){
        const int t = m0 + wm + mi * 16 + q * 4 + r;
        const float g = gates[t * NE + e];
        #pragma unroll
        for (int ni = 0; ni < 4; ni++){
          float v = acc[mi][ni][r] + bset[ni];
          float h = 0.5f * v * (1.0f + erff(v * 0.70710678118654752f));
          C[(size_t)t * ldc + n0 + wn + ni * 16 + ln] = (__bf16)(g * h);
        }
      }
    }
  } else {
    float* fsm = (float*)As;
    float* gl  = fsm;          // [128][8] gates
    float* b2l = fsm + 1024;   // [8][128] b2 slice
    for (int i = tid; i < 1024; i += 256){
      gl[i] = gates[m0 * NE + i];
      const int e = i >> 7, dl = i & 127;
      b2l[i] = (float)bias[e * DM + n0 + dl];
    }
    __syncthreads();
    #pragma unroll
    for (int mi = 0; mi < 4; mi++){
      #pragma unroll
      for (int r = 0; r < 4; r++){
        const int tr = wm + mi * 16 + q * 4 + r;
        const int t = m0 + tr;
        #pragma unroll
        for (int ni = 0; ni < 4; ni++){
          const int nl = wn + ni * 16 + ln;
          float v = acc[mi][ni][r];
          #pragma unroll
          for (int e = 0; e < NE; e++) v += gl[tr * 8 + e] * b2l[e * 128 + nl];
          if (md) ((__bf16*)Cp)[(size_t)t * ldc + n0 + nl] = (__bf16)v;
          else    ((float*)Cp)[(size_t)t * ldc + n0 + nl] = v;
        }
      }
    }
  }
}

extern "C" void kernel_launch(void* const* d_in, const int* in_sizes, int n_in,
                              void* d_out, int out_size, void* d_ws, size_t ws_size,
                              hipStream_t stream)
{
  // ws layout: [0,256) flag | [256, 262400) gates f32 | [262400, +32.05MB) conv bf16
  //            | Hp bf16 64MB
  int*    flag  = (int*)d_ws;
  float*  gates = (float*)((char*)d_ws + 256);
  __bf16* conv  = (__bf16*)((char*)d_ws + 262400);
  __bf16* Hp    = (__bf16*)((char*)d_ws + 262400 + (size_t)CO_TOT * 2);

  detect_k<<<1, 256, 0, stream>>>(d_in[0], flag);
  convert_k<<<CO_TOT / 1024, 256, 0, stream>>>(
      (const float*)d_in[0], (const float*)d_in[1], (const float*)d_in[2],
      (const float*)d_in[3], (const float*)d_in[4], (const float*)d_in[5],
      (const float*)d_in[6], conv, flag);
  route_k<<<T_TOK / 4, 256, 0, stream>>>(d_in[0], d_in[5], d_in[6], flag, gates);
  gemm_k<0><<<dim3(T_TOK / 128, DFF / 128), 256, 0, stream>>>(
      d_in[0], d_in[1], d_in[2], conv, flag, gates, Hp);
  gemm_k<1><<<dim3(T_TOK / 128, DM / 128), 256, 0, stream>>>(
      Hp, d_in[3], d_in[4], conv, flag, gates, d_out);
}